// Round 7
// baseline (250.028 us; speedup 1.0000x reference)
//
#include <hip/hip_runtime.h>
#include <stdint.h>

#define MD 8192
#define ND 8192
#define KD 2048
#define KTH 15099494  // int(8192*2048*0.9)

#define NCOPY 16   // privatized LDS histogram copies
#define HSTR 257   // copy stride in words; 257 % 32 == 1 -> distinct banks per copy
#define NPART 8    // global histogram partials

typedef int v4i  __attribute__((ext_vector_type(4)));
typedef int v16i __attribute__((ext_vector_type(16)));

__device__ __forceinline__ void gload_lds16(const void* g, void* l) {
  __builtin_amdgcn_global_load_lds(
      (const __attribute__((address_space(1))) uint32_t*)g,
      (__attribute__((address_space(3))) uint32_t*)l, 16, 0, 0);
}

// ---------------- absmax: both tensors, ONE global atomic per block ----------------
__global__ void absmax2_kernel(const float* __restrict__ x1, const float* __restrict__ x2,
                               unsigned int* sbits) {
  __shared__ float wred[4];
  const float4* p = (const float4*)(blockIdx.y ? x2 : x1);
  const int n4 = MD * KD / 4;
  int tid = blockIdx.x * blockDim.x + threadIdx.x;
  int stride = gridDim.x * blockDim.x;
  float m = 0.f;
  for (int i = tid; i < n4; i += stride) {
    float4 v = p[i];
    m = fmaxf(m, fmaxf(fmaxf(fabsf(v.x), fabsf(v.y)), fmaxf(fabsf(v.z), fabsf(v.w))));
  }
  #pragma unroll
  for (int off = 32; off; off >>= 1) m = fmaxf(m, __shfl_down(m, off, 64));
  if ((threadIdx.x & 63) == 0) wred[threadIdx.x >> 6] = m;
  __syncthreads();
  if (threadIdx.x == 0) {
    float bm = fmaxf(fmaxf(wred[0], wred[1]), fmaxf(wred[2], wred[3]));
    atomicMax(&sbits[blockIdx.y], __float_as_uint(bm));
  }
}

// ---------------- quantize x1 (row-major keep) + privatized histogram ----------------
__global__ void quant_hist_kernel(const float* __restrict__ x, int8_t* __restrict__ q,
                                  int n4, const unsigned int* sbits, unsigned int* hist) {
  __shared__ unsigned int h[NCOPY * HSTR];
  for (int i = threadIdx.x; i < NCOPY * HSTR; i += blockDim.x) h[i] = 0;
  __syncthreads();
  unsigned int* hc = h + (threadIdx.x & (NCOPY - 1)) * HSTR;
  float s = __uint_as_float(*sbits);
  int tid = blockIdx.x * blockDim.x + threadIdx.x;
  int stride = gridDim.x * blockDim.x;
  const float4* p = (const float4*)x;
  uint32_t* qo = (uint32_t*)q;
  for (int i = tid; i < n4; i += stride) {
    float4 v = p[i];
    int q0 = (int)rintf(v.x / s * 127.0f);   // keep (x/s)*127 order: matches np bit-exactly
    int q1 = (int)rintf(v.y / s * 127.0f);
    int q2 = (int)rintf(v.z / s * 127.0f);
    int q3 = (int)rintf(v.w / s * 127.0f);
    atomicAdd(&hc[q0 + 127], 1u);
    atomicAdd(&hc[q1 + 127], 1u);
    atomicAdd(&hc[q2 + 127], 1u);
    atomicAdd(&hc[q3 + 127], 1u);
    uint32_t packed = (uint32_t)(uint8_t)(int8_t)q0 |
                      ((uint32_t)(uint8_t)(int8_t)q1 << 8) |
                      ((uint32_t)(uint8_t)(int8_t)q2 << 16) |
                      ((uint32_t)(uint8_t)(int8_t)q3 << 24);
    qo[i] = packed;
  }
  __syncthreads();
  {
    int b = threadIdx.x;
    unsigned int sum = 0;
    #pragma unroll
    for (int c = 0; c < NCOPY; ++c) sum += h[c * HSTR + b];
    if (sum) atomicAdd(&hist[(blockIdx.x & (NPART - 1)) * 256 + b], sum);
  }
}

// ---------------- quantize x2 transposed ([K][N] -> q2t[N][K]) + privatized histogram ----
#define TSTR 17
__global__ void transq_kernel(const float* __restrict__ x, int8_t* __restrict__ qt,
                              const unsigned int* sbits, unsigned int* hist) {
  __shared__ unsigned int tile2[64 * TSTR];
  __shared__ unsigned int h[NCOPY * HSTR];
  for (int i = threadIdx.x; i < NCOPY * HSTR; i += blockDim.x) h[i] = 0;
  __syncthreads();
  unsigned int* hc = h + (threadIdx.x & (NCOPY - 1)) * HSTR;
  float s = __uint_as_float(*sbits);
  int n0 = blockIdx.x * 64, k0 = blockIdx.y * 64;
  int t = threadIdx.x;
  int nq = t & 15, kq = t >> 4;
  unsigned int pk[4] = {0, 0, 0, 0};
  #pragma unroll
  for (int j = 0; j < 4; ++j) {
    float4 v = *(const float4*)(x + (size_t)(k0 + kq * 4 + j) * ND + n0 + nq * 4);
    int q0 = (int)rintf(v.x / s * 127.0f);
    int q1 = (int)rintf(v.y / s * 127.0f);
    int q2 = (int)rintf(v.z / s * 127.0f);
    int q3 = (int)rintf(v.w / s * 127.0f);
    atomicAdd(&hc[q0 + 127], 1u);
    atomicAdd(&hc[q1 + 127], 1u);
    atomicAdd(&hc[q2 + 127], 1u);
    atomicAdd(&hc[q3 + 127], 1u);
    pk[0] |= ((unsigned int)(uint8_t)(int8_t)q0) << (8 * j);
    pk[1] |= ((unsigned int)(uint8_t)(int8_t)q1) << (8 * j);
    pk[2] |= ((unsigned int)(uint8_t)(int8_t)q2) << (8 * j);
    pk[3] |= ((unsigned int)(uint8_t)(int8_t)q3) << (8 * j);
  }
  #pragma unroll
  for (int i = 0; i < 4; ++i) tile2[(nq * 4 + i) * TSTR + kq] = pk[i];
  __syncthreads();
  {
    int n = t >> 2, c = t & 3;
    uint4 val;
    val.x = tile2[n * TSTR + c * 4 + 0];
    val.y = tile2[n * TSTR + c * 4 + 1];
    val.z = tile2[n * TSTR + c * 4 + 2];
    val.w = tile2[n * TSTR + c * 4 + 3];
    *(uint4*)(qt + (size_t)(n0 + n) * KD + k0 + c * 16) = val;
  }
  __syncthreads();
  {
    int b = threadIdx.x;
    unsigned int sum = 0;
    #pragma unroll
    for (int c = 0; c < NCOPY; ++c) sum += h[c * HSTR + b];
    if (sum) atomicAdd(&hist[((blockIdx.x + blockIdx.y) & (NPART - 1)) * 256 + b], sum);
  }
}

// ---------------- kth-value: sum partials, prefix scan, pick crossing ----------------
__global__ void finalize_kernel(const unsigned int* __restrict__ hist1,
                                const unsigned int* __restrict__ hist2,
                                float* __restrict__ out_k) {
  __shared__ unsigned int c[256];
  __shared__ int result;
  int t = threadIdx.x;
  const unsigned int* h = (blockIdx.x == 0) ? hist1 : hist2;
  unsigned int sum = 0;
  #pragma unroll
  for (int p = 0; p < NPART; ++p) sum += h[p * 256 + t];
  c[t] = sum;
  if (t == 0) result = 127;
  __syncthreads();
  #pragma unroll
  for (int off = 1; off < 256; off <<= 1) {
    unsigned int add = (t >= off) ? c[t - off] : 0u;
    __syncthreads();
    c[t] += add;
    __syncthreads();
  }
  unsigned int prev = (t == 0) ? 0u : c[t - 1];
  if (c[t] >= (unsigned int)KTH && prev < (unsigned int)KTH) result = t - 127;
  __syncthreads();
  if (t == 0) out_k[blockIdx.x] = (float)result;
}

// ---------------- i8 GEMM: 32x32x32 MFMA + m201-faithful phase ordering -----------
// 256x256 tile, 512 thr (8 waves 2Mx4N), wave tile 128x64 = 4x2 tiles of 32x32.
// K-tile BK=64 = 2 phases (kk=0,1), each: {6 ds_read_b128 + 2 gload_lds issued
// PRE-barrier} -> BAR -> lgkmcnt(0) -> setprio(1) 8 MFMA setprio(0) -> BAR.
// Read latency hides under barrier wait (m201 ordering). vmcnt(4) once per
// K-tile (phase B): confirms tile k+1 with tile k+2's 4 loads in flight
// (~1500cy to land > 900cy HBM latency). LDS: 4 regions x 16KB x {A,B} = 128KB.
// Race: tile k confirmed by vmcnt(4)+BAR in tile k-1 phase B, before tile k
// phase A's pre-BAR reads; STAGE(k+2) targets region (k-2)&3, last read 4
// barriers earlier. Swizzle chunk ^= (row>>1)&3 on both sides (involution).
#define NKT 32  // KD/64
__global__ __launch_bounds__(512, 2) void gemm_i8_kernel(
    const int8_t* __restrict__ qa, const int8_t* __restrict__ qb,
    float* __restrict__ out, const unsigned int* __restrict__ sbits) {
  extern __shared__ __align__(16) int8_t L[];  // A regions [0,64K), B regions [64K,128K)

  int bid = blockIdx.x;
  int xcd = bid & 7;
  int local = bid >> 3;
  int brow = xcd * 4 + (local & 3);   // 0..31
  int bcol = local >> 2;              // 0..31

  int t = threadIdx.x;
  int lane = t & 63;
  int w = t >> 6;
  int wr = (w >> 2) * 128;   // 0 | 128
  int wc = (w & 3) * 64;     // 0,64,128,192

  v16i acc[4][2] = {};

  const int8_t* ga = qa + (size_t)brow * 256 * KD;
  const int8_t* gb = qb + (size_t)bcol * 256 * KD;

  int srow = t >> 2;   // 0..127 (row within a 128-row half)
  int sc = t & 3;

  auto STAGE_HALF = [&](int k, int half) {  // 2 gload_lds (1 A + 1 B)
    int reg = (k & 3) * 16384;
    int row = half * 128 + srow;
    int gc = sc ^ ((row >> 1) & 3);   // pre-swizzled source, linear LDS dest
    gload_lds16(ga + (size_t)row * KD + k * 64 + gc * 16, L + reg + row * 64 + sc * 16);
    gload_lds16(gb + (size_t)row * KD + k * 64 + gc * 16, L + 65536 + reg + row * 64 + sc * 16);
  };

  // one phase: reads(kk) + stage pre-BAR, MFMA post-BAR. vm: -1 none, 4, 0.
  auto PHASE = [&](int k, int kk, bool stage, int half, int vm) {
    const int8_t* LA = L + (k & 3) * 16384;
    const int8_t* LB = L + 65536 + (k & 3) * 16384;
    v4i aF[4], bF[2];
    #pragma unroll
    for (int n = 0; n < 2; ++n) {
      int row = wc + n * 32 + (lane & 31);
      int c = (kk * 2 + (lane >> 5)) ^ ((row >> 1) & 3);
      bF[n] = *(const v4i*)(LB + row * 64 + c * 16);
    }
    #pragma unroll
    for (int m = 0; m < 4; ++m) {
      int row = wr + m * 32 + (lane & 31);
      int c = (kk * 2 + (lane >> 5)) ^ ((row >> 1) & 3);
      aF[m] = *(const v4i*)(LA + row * 64 + c * 16);
    }
    if (stage) STAGE_HALF(k + 2, half);
    if (vm == 4)      asm volatile("s_waitcnt vmcnt(4)" ::: "memory");
    else if (vm == 0) asm volatile("s_waitcnt vmcnt(0)" ::: "memory");
    __builtin_amdgcn_sched_barrier(0);
    __builtin_amdgcn_s_barrier();
    asm volatile("s_waitcnt lgkmcnt(0)" ::: "memory");
    __builtin_amdgcn_sched_barrier(0);
    __builtin_amdgcn_s_setprio(1);
    #pragma unroll
    for (int m = 0; m < 4; ++m)
      #pragma unroll
      for (int n = 0; n < 2; ++n)
        acc[m][n] = __builtin_amdgcn_mfma_i32_32x32x32_i8(aF[m], bF[n], acc[m][n], 0, 0, 0);
    __builtin_amdgcn_s_setprio(0);
    __builtin_amdgcn_sched_barrier(0);
    __builtin_amdgcn_s_barrier();
    __builtin_amdgcn_sched_barrier(0);
  };

  // prologue: tiles 0,1 fully staged; confirm tile 0 (vmcnt(4): tile 1 in flight)
  STAGE_HALF(0, 0); STAGE_HALF(0, 1);
  STAGE_HALF(1, 0); STAGE_HALF(1, 1);
  asm volatile("s_waitcnt vmcnt(4)" ::: "memory");
  __builtin_amdgcn_s_barrier();

  for (int k = 0; k < NKT - 2; ++k) {
    PHASE(k, 0, true, 0, -1);
    PHASE(k, 1, true, 1, 4);   // confirms tile k+1; tile k+2's 4 loads in flight
  }
  PHASE(NKT - 2, 0, false, 0, -1);
  PHASE(NKT - 2, 1, false, 1, 0);
  PHASE(NKT - 1, 0, false, 0, -1);
  PHASE(NKT - 1, 1, false, 1, -1);

  float s1 = __uint_as_float(sbits[0]);
  float s2 = __uint_as_float(sbits[1]);
  float scale = s1 * s2 / (127.0f * 127.0f);
  // C/D 32x32: col = lane&31, row = (reg&3) + 8*(reg>>2) + 4*(lane>>5)
  int orow0 = brow * 256 + wr + 4 * (lane >> 5);
  int ocol0 = bcol * 256 + wc + (lane & 31);
  #pragma unroll
  for (int m = 0; m < 4; ++m)
    #pragma unroll
    for (int n = 0; n < 2; ++n)
      #pragma unroll
      for (int r = 0; r < 16; ++r) {
        int row = orow0 + m * 32 + (r & 3) + 8 * (r >> 2);
        out[(size_t)row * ND + ocol0 + n * 32] = (float)acc[m][n][r] * scale;
      }
}

extern "C" void kernel_launch(void* const* d_in, const int* in_sizes, int n_in,
                              void* d_out, int out_size, void* d_ws, size_t ws_size,
                              hipStream_t stream) {
  const float* x1 = (const float*)d_in[0];
  const float* x2 = (const float*)d_in[1];
  float* out = (float*)d_out;
  uint8_t* ws = (uint8_t*)d_ws;

  unsigned int* sbits = (unsigned int*)ws;
  unsigned int* hist1 = (unsigned int*)(ws + 256);
  unsigned int* hist2 = (unsigned int*)(ws + 256 + 8192);
  int8_t* q1  = (int8_t*)(ws + 32768);
  int8_t* q2t = q1 + (size_t)MD * KD;

  const int n4_1 = MD * KD / 4;
  const int n4_2 = KD * ND / 4;

  hipFuncSetAttribute((const void*)gemm_i8_kernel,
                      hipFuncAttributeMaxDynamicSharedMemorySize, 131072);

  hipMemsetAsync(ws, 0, 32768, stream);
  absmax2_kernel<<<dim3(512, 2), 256, 0, stream>>>(x1, x2, sbits);
  quant_hist_kernel<<<1024, 256, 0, stream>>>(x1, q1, n4_1, sbits + 0, hist1);
  transq_kernel<<<dim3(ND / 64, KD / 64), 256, 0, stream>>>(x2, q2t, sbits + 1, hist2);
  finalize_kernel<<<2, 256, 0, stream>>>(hist1, hist2, out + (size_t)MD * ND);
  gemm_i8_kernel<<<1024, 512, 131072, stream>>>(q1, q2t, out, sbits);
}

// Round 8
// 228.459 us; speedup vs baseline: 1.0944x; 1.0944x over previous
//
#include <hip/hip_runtime.h>
#include <stdint.h>

#define MD 8192
#define ND 8192
#define KD 2048
#define KTH 15099494  // int(8192*2048*0.9)

#define NCOPY 16   // privatized LDS histogram copies
#define HSTR 257   // copy stride in words; 257 % 32 == 1 -> distinct banks per copy
#define NPART 8    // global histogram partials

typedef int v4i __attribute__((ext_vector_type(4)));

__device__ __forceinline__ void gload_lds16(const void* g, void* l) {
  __builtin_amdgcn_global_load_lds(
      (const __attribute__((address_space(1))) uint32_t*)g,
      (__attribute__((address_space(3))) uint32_t*)l, 16, 0, 0);
}

// ---------------- absmax: both tensors, ONE global atomic per block ----------------
__global__ void absmax2_kernel(const float* __restrict__ x1, const float* __restrict__ x2,
                               unsigned int* sbits) {
  __shared__ float wred[4];
  const float4* p = (const float4*)(blockIdx.y ? x2 : x1);
  const int n4 = MD * KD / 4;
  int tid = blockIdx.x * blockDim.x + threadIdx.x;
  int stride = gridDim.x * blockDim.x;
  float m = 0.f;
  for (int i = tid; i < n4; i += stride) {
    float4 v = p[i];
    m = fmaxf(m, fmaxf(fmaxf(fabsf(v.x), fabsf(v.y)), fmaxf(fabsf(v.z), fabsf(v.w))));
  }
  #pragma unroll
  for (int off = 32; off; off >>= 1) m = fmaxf(m, __shfl_down(m, off, 64));
  if ((threadIdx.x & 63) == 0) wred[threadIdx.x >> 6] = m;
  __syncthreads();
  if (threadIdx.x == 0) {
    float bm = fmaxf(fmaxf(wred[0], wred[1]), fmaxf(wred[2], wred[3]));
    atomicMax(&sbits[blockIdx.y], __float_as_uint(bm));
  }
}

// ---------------- quantize x1 (row-major keep) + privatized histogram ----------------
__global__ void quant_hist_kernel(const float* __restrict__ x, int8_t* __restrict__ q,
                                  int n4, const unsigned int* sbits, unsigned int* hist) {
  __shared__ unsigned int h[NCOPY * HSTR];
  for (int i = threadIdx.x; i < NCOPY * HSTR; i += blockDim.x) h[i] = 0;
  __syncthreads();
  unsigned int* hc = h + (threadIdx.x & (NCOPY - 1)) * HSTR;
  float s = __uint_as_float(*sbits);
  int tid = blockIdx.x * blockDim.x + threadIdx.x;
  int stride = gridDim.x * blockDim.x;
  const float4* p = (const float4*)x;
  uint32_t* qo = (uint32_t*)q;
  for (int i = tid; i < n4; i += stride) {
    float4 v = p[i];
    int q0 = (int)rintf(v.x / s * 127.0f);   // keep (x/s)*127 order: matches np bit-exactly
    int q1 = (int)rintf(v.y / s * 127.0f);
    int q2 = (int)rintf(v.z / s * 127.0f);
    int q3 = (int)rintf(v.w / s * 127.0f);
    atomicAdd(&hc[q0 + 127], 1u);
    atomicAdd(&hc[q1 + 127], 1u);
    atomicAdd(&hc[q2 + 127], 1u);
    atomicAdd(&hc[q3 + 127], 1u);
    uint32_t packed = (uint32_t)(uint8_t)(int8_t)q0 |
                      ((uint32_t)(uint8_t)(int8_t)q1 << 8) |
                      ((uint32_t)(uint8_t)(int8_t)q2 << 16) |
                      ((uint32_t)(uint8_t)(int8_t)q3 << 24);
    qo[i] = packed;
  }
  __syncthreads();
  {
    int b = threadIdx.x;
    unsigned int sum = 0;
    #pragma unroll
    for (int c = 0; c < NCOPY; ++c) sum += h[c * HSTR + b];
    if (sum) atomicAdd(&hist[(blockIdx.x & (NPART - 1)) * 256 + b], sum);
  }
}

// ---------------- quantize x2 transposed ([K][N] -> q2t[N][K]) + privatized histogram ----
#define TSTR 17
__global__ void transq_kernel(const float* __restrict__ x, int8_t* __restrict__ qt,
                              const unsigned int* sbits, unsigned int* hist) {
  __shared__ unsigned int tile2[64 * TSTR];
  __shared__ unsigned int h[NCOPY * HSTR];
  for (int i = threadIdx.x; i < NCOPY * HSTR; i += blockDim.x) h[i] = 0;
  __syncthreads();
  unsigned int* hc = h + (threadIdx.x & (NCOPY - 1)) * HSTR;
  float s = __uint_as_float(*sbits);
  int n0 = blockIdx.x * 64, k0 = blockIdx.y * 64;
  int t = threadIdx.x;
  int nq = t & 15, kq = t >> 4;
  unsigned int pk[4] = {0, 0, 0, 0};
  #pragma unroll
  for (int j = 0; j < 4; ++j) {
    float4 v = *(const float4*)(x + (size_t)(k0 + kq * 4 + j) * ND + n0 + nq * 4);
    int q0 = (int)rintf(v.x / s * 127.0f);
    int q1 = (int)rintf(v.y / s * 127.0f);
    int q2 = (int)rintf(v.z / s * 127.0f);
    int q3 = (int)rintf(v.w / s * 127.0f);
    atomicAdd(&hc[q0 + 127], 1u);
    atomicAdd(&hc[q1 + 127], 1u);
    atomicAdd(&hc[q2 + 127], 1u);
    atomicAdd(&hc[q3 + 127], 1u);
    pk[0] |= ((unsigned int)(uint8_t)(int8_t)q0) << (8 * j);
    pk[1] |= ((unsigned int)(uint8_t)(int8_t)q1) << (8 * j);
    pk[2] |= ((unsigned int)(uint8_t)(int8_t)q2) << (8 * j);
    pk[3] |= ((unsigned int)(uint8_t)(int8_t)q3) << (8 * j);
  }
  #pragma unroll
  for (int i = 0; i < 4; ++i) tile2[(nq * 4 + i) * TSTR + kq] = pk[i];
  __syncthreads();
  {
    int n = t >> 2, c = t & 3;
    uint4 val;
    val.x = tile2[n * TSTR + c * 4 + 0];
    val.y = tile2[n * TSTR + c * 4 + 1];
    val.z = tile2[n * TSTR + c * 4 + 2];
    val.w = tile2[n * TSTR + c * 4 + 3];
    *(uint4*)(qt + (size_t)(n0 + n) * KD + k0 + c * 16) = val;
  }
  __syncthreads();
  {
    int b = threadIdx.x;
    unsigned int sum = 0;
    #pragma unroll
    for (int c = 0; c < NCOPY; ++c) sum += h[c * HSTR + b];
    if (sum) atomicAdd(&hist[((blockIdx.x + blockIdx.y) & (NPART - 1)) * 256 + b], sum);
  }
}

// ---------------- kth-value: sum partials, prefix scan, pick crossing ----------------
__global__ void finalize_kernel(const unsigned int* __restrict__ hist1,
                                const unsigned int* __restrict__ hist2,
                                float* __restrict__ out_k) {
  __shared__ unsigned int c[256];
  __shared__ int result;
  int t = threadIdx.x;
  const unsigned int* h = (blockIdx.x == 0) ? hist1 : hist2;
  unsigned int sum = 0;
  #pragma unroll
  for (int p = 0; p < NPART; ++p) sum += h[p * 256 + t];
  c[t] = sum;
  if (t == 0) result = 127;
  __syncthreads();
  #pragma unroll
  for (int off = 1; off < 256; off <<= 1) {
    unsigned int add = (t >= off) ? c[t - off] : 0u;
    __syncthreads();
    c[t] += add;
    __syncthreads();
  }
  unsigned int prev = (t == 0) ? 0u : c[t - 1];
  if (c[t] >= (unsigned int)KTH && prev < (unsigned int)KTH) result = t - 127;
  __syncthreads();
  if (t == 0) out_k[blockIdx.x] = (float)result;
}

// ---------------- i8 GEMM: 2-blocks/CU deep pipeline ----------------
// 256x128 tile, 512 thr (8 waves 4Mx2N), wave tile 64x64 -> acc 4x4 v4i = 64
// AGPR, ~120 regs/wave -> __launch_bounds__(512,4) = 4 waves/SIMD from TWO
// independent blocks/CU (48KB LDS x2 = 96KB). Cross-block desync provides the
// read<->MFMA overlap (m114) that lockstep 1-block/CU schedules couldn't.
// BK=64 double-buffer, counted vmcnt(3) (tile k+1's 3 loads stay in flight),
// 2 barriers/K-tile. 16x16x64 MFMA, 16-row fragment swizzle (0-conflict).
#define NKT 32  // KD/64
__global__ __launch_bounds__(512, 4) void gemm_i8_kernel(
    const int8_t* __restrict__ qa, const int8_t* __restrict__ qb,
    float* __restrict__ out, const unsigned int* __restrict__ sbits) {
  extern __shared__ __align__(16) int8_t L[];  // A bufs [0,32K), B bufs [32K,48K)

  // XCD map (bijective, 2048 = 8*4*64): xcd owns 4-brow stripe x 64 bcols
  int bid = blockIdx.x;
  int xcd = bid & 7;
  int local = bid >> 3;               // 0..255
  int brow = xcd * 4 + (local & 3);   // 0..31  (256-row panels)
  int bcol = local >> 2;              // 0..63  (128-col panels)

  int t = threadIdx.x;
  int lane = t & 63;
  int w = t >> 6;
  int wr = (w >> 1) * 64;   // 0,64,128,192
  int wc = (w & 1) * 64;    // 0,64

  v4i acc[4][4] = {};

  const int8_t* ga = qa + (size_t)brow * 256 * KD;
  const int8_t* gb = qb + (size_t)bcol * 128 * KD;

  int srow = t >> 2;   // 0..127
  int sc = t & 3;

  auto STAGE = [&](int k, int buf) {  // 3 gload_lds: 2 A-halves + 1 B
    int8_t* LA = L + buf * 16384;
    int8_t* LB = L + 32768 + buf * 8192;
    int kcol = k * 64;
    #pragma unroll
    for (int j = 0; j < 2; ++j) {
      int row = j * 128 + srow;
      int gc = sc ^ ((row >> 1) & 3);   // pre-swizzled source, linear LDS dest
      gload_lds16(ga + (size_t)row * KD + kcol + gc * 16, LA + row * 64 + sc * 16);
    }
    {
      int row = srow;
      int gc = sc ^ ((row >> 1) & 3);
      gload_lds16(gb + (size_t)row * KD + kcol + gc * 16, LB + row * 64 + sc * 16);
    }
  };

  auto COMPUTE = [&](int k) {
    const int8_t* LA = L + (k & 1) * 16384;
    const int8_t* LB = L + 32768 + (k & 1) * 8192;
    v4i aF[4], bF[4];
    #pragma unroll
    for (int n = 0; n < 4; ++n) {
      int row = wc + n * 16 + (lane & 15);
      int c = (lane >> 4) ^ ((row >> 1) & 3);
      bF[n] = *(const v4i*)(LB + row * 64 + c * 16);
    }
    #pragma unroll
    for (int m = 0; m < 4; ++m) {
      int row = wr + m * 16 + (lane & 15);
      int c = (lane >> 4) ^ ((row >> 1) & 3);
      aF[m] = *(const v4i*)(LA + row * 64 + c * 16);
    }
    __builtin_amdgcn_s_setprio(1);
    #pragma unroll
    for (int m = 0; m < 4; ++m)
      #pragma unroll
      for (int n = 0; n < 4; ++n)
        acc[m][n] = __builtin_amdgcn_mfma_i32_16x16x64_i8(aF[m], bF[n], acc[m][n], 0, 0, 0);
    __builtin_amdgcn_s_setprio(0);
  };

  STAGE(0, 0);
  asm volatile("s_waitcnt vmcnt(0)" ::: "memory");
  __builtin_amdgcn_s_barrier();

  for (int k = 0; k < NKT; ++k) {
    // stage k+1 (overwrites buf of k-1; end-of-iter barrier made that safe)
    if (k + 1 < NKT) {
      STAGE(k + 1, (k + 1) & 1);
      asm volatile("s_waitcnt vmcnt(3)" ::: "memory");  // tile k landed; k+1 in flight
    } else {
      asm volatile("s_waitcnt vmcnt(0)" ::: "memory");
    }
    __builtin_amdgcn_s_barrier();          // all waves see tile k complete
    __builtin_amdgcn_sched_barrier(0);
    COMPUTE(k);
    __builtin_amdgcn_sched_barrier(0);
    __builtin_amdgcn_s_barrier();          // all reads of tile k done -> buf reusable
  }

  float s1 = __uint_as_float(sbits[0]);
  float s2 = __uint_as_float(sbits[1]);
  float scale = s1 * s2 / (127.0f * 127.0f);
  int orow = brow * 256 + wr + ((lane >> 4) * 4);
  int ocol = bcol * 128 + wc + (lane & 15);
  #pragma unroll
  for (int m = 0; m < 4; ++m)
    #pragma unroll
    for (int n = 0; n < 4; ++n)
      #pragma unroll
      for (int r = 0; r < 4; ++r)
        out[(size_t)(orow + m * 16 + r) * ND + (ocol + n * 16)] = (float)acc[m][n][r] * scale;
}

extern "C" void kernel_launch(void* const* d_in, const int* in_sizes, int n_in,
                              void* d_out, int out_size, void* d_ws, size_t ws_size,
                              hipStream_t stream) {
  const float* x1 = (const float*)d_in[0];
  const float* x2 = (const float*)d_in[1];
  float* out = (float*)d_out;
  uint8_t* ws = (uint8_t*)d_ws;

  unsigned int* sbits = (unsigned int*)ws;
  unsigned int* hist1 = (unsigned int*)(ws + 256);
  unsigned int* hist2 = (unsigned int*)(ws + 256 + 8192);
  int8_t* q1  = (int8_t*)(ws + 32768);
  int8_t* q2t = q1 + (size_t)MD * KD;

  const int n4_1 = MD * KD / 4;
  const int n4_2 = KD * ND / 4;

  hipFuncSetAttribute((const void*)gemm_i8_kernel,
                      hipFuncAttributeMaxDynamicSharedMemorySize, 49152);

  hipMemsetAsync(ws, 0, 32768, stream);
  absmax2_kernel<<<dim3(512, 2), 256, 0, stream>>>(x1, x2, sbits);
  quant_hist_kernel<<<1024, 256, 0, stream>>>(x1, q1, n4_1, sbits + 0, hist1);
  transq_kernel<<<dim3(ND / 64, KD / 64), 256, 0, stream>>>(x2, q2t, sbits + 1, hist2);
  finalize_kernel<<<2, 256, 0, stream>>>(hist1, hist2, out + (size_t)MD * ND);
  gemm_i8_kernel<<<2048, 512, 49152, stream>>>(q1, q2t, out, sbits);
}

// Round 9
// 228.425 us; speedup vs baseline: 1.0946x; 1.0002x over previous
//
#include <hip/hip_runtime.h>
#include <stdint.h>

#define MD 8192
#define ND 8192
#define KD 2048
#define KTH 15099494  // int(8192*2048*0.9)

#define NCOPY 16   // privatized LDS histogram copies
#define HSTR 257   // copy stride in words; 257 % 32 == 1 -> distinct banks per copy
#define NPART 8    // global histogram partials

typedef int v4i __attribute__((ext_vector_type(4)));

__device__ __forceinline__ void gload_lds16(const void* g, void* l) {
  __builtin_amdgcn_global_load_lds(
      (const __attribute__((address_space(1))) uint32_t*)g,
      (__attribute__((address_space(3))) uint32_t*)l, 16, 0, 0);
}

// ---------------- absmax: both tensors, ONE global atomic per block ----------------
__global__ void absmax2_kernel(const float* __restrict__ x1, const float* __restrict__ x2,
                               unsigned int* sbits) {
  __shared__ float wred[4];
  const float4* p = (const float4*)(blockIdx.y ? x2 : x1);
  const int n4 = MD * KD / 4;
  int tid = blockIdx.x * blockDim.x + threadIdx.x;
  int stride = gridDim.x * blockDim.x;
  float m = 0.f;
  for (int i = tid; i < n4; i += stride) {
    float4 v = p[i];
    m = fmaxf(m, fmaxf(fmaxf(fabsf(v.x), fabsf(v.y)), fmaxf(fabsf(v.z), fabsf(v.w))));
  }
  #pragma unroll
  for (int off = 32; off; off >>= 1) m = fmaxf(m, __shfl_down(m, off, 64));
  if ((threadIdx.x & 63) == 0) wred[threadIdx.x >> 6] = m;
  __syncthreads();
  if (threadIdx.x == 0) {
    float bm = fmaxf(fmaxf(wred[0], wred[1]), fmaxf(wred[2], wred[3]));
    atomicMax(&sbits[blockIdx.y], __float_as_uint(bm));
  }
}

// ---------------- quantize x1 (row-major keep) + privatized histogram ----------------
__global__ void quant_hist_kernel(const float* __restrict__ x, int8_t* __restrict__ q,
                                  int n4, const unsigned int* sbits, unsigned int* hist) {
  __shared__ unsigned int h[NCOPY * HSTR];
  for (int i = threadIdx.x; i < NCOPY * HSTR; i += blockDim.x) h[i] = 0;
  __syncthreads();
  unsigned int* hc = h + (threadIdx.x & (NCOPY - 1)) * HSTR;
  float s = __uint_as_float(*sbits);
  int tid = blockIdx.x * blockDim.x + threadIdx.x;
  int stride = gridDim.x * blockDim.x;
  const float4* p = (const float4*)x;
  uint32_t* qo = (uint32_t*)q;
  for (int i = tid; i < n4; i += stride) {
    float4 v = p[i];
    int q0 = (int)rintf(v.x / s * 127.0f);   // keep (x/s)*127 order: matches np bit-exactly
    int q1 = (int)rintf(v.y / s * 127.0f);
    int q2 = (int)rintf(v.z / s * 127.0f);
    int q3 = (int)rintf(v.w / s * 127.0f);
    atomicAdd(&hc[q0 + 127], 1u);
    atomicAdd(&hc[q1 + 127], 1u);
    atomicAdd(&hc[q2 + 127], 1u);
    atomicAdd(&hc[q3 + 127], 1u);
    uint32_t packed = (uint32_t)(uint8_t)(int8_t)q0 |
                      ((uint32_t)(uint8_t)(int8_t)q1 << 8) |
                      ((uint32_t)(uint8_t)(int8_t)q2 << 16) |
                      ((uint32_t)(uint8_t)(int8_t)q3 << 24);
    qo[i] = packed;
  }
  __syncthreads();
  {
    int b = threadIdx.x;
    unsigned int sum = 0;
    #pragma unroll
    for (int c = 0; c < NCOPY; ++c) sum += h[c * HSTR + b];
    if (sum) atomicAdd(&hist[(blockIdx.x & (NPART - 1)) * 256 + b], sum);
  }
}

// ---------------- quantize x2 transposed ([K][N] -> q2t[N][K]) + privatized histogram ----
#define TSTR 17
__global__ void transq_kernel(const float* __restrict__ x, int8_t* __restrict__ qt,
                              const unsigned int* sbits, unsigned int* hist) {
  __shared__ unsigned int tile2[64 * TSTR];
  __shared__ unsigned int h[NCOPY * HSTR];
  for (int i = threadIdx.x; i < NCOPY * HSTR; i += blockDim.x) h[i] = 0;
  __syncthreads();
  unsigned int* hc = h + (threadIdx.x & (NCOPY - 1)) * HSTR;
  float s = __uint_as_float(*sbits);
  int n0 = blockIdx.x * 64, k0 = blockIdx.y * 64;
  int t = threadIdx.x;
  int nq = t & 15, kq = t >> 4;
  unsigned int pk[4] = {0, 0, 0, 0};
  #pragma unroll
  for (int j = 0; j < 4; ++j) {
    float4 v = *(const float4*)(x + (size_t)(k0 + kq * 4 + j) * ND + n0 + nq * 4);
    int q0 = (int)rintf(v.x / s * 127.0f);
    int q1 = (int)rintf(v.y / s * 127.0f);
    int q2 = (int)rintf(v.z / s * 127.0f);
    int q3 = (int)rintf(v.w / s * 127.0f);
    atomicAdd(&hc[q0 + 127], 1u);
    atomicAdd(&hc[q1 + 127], 1u);
    atomicAdd(&hc[q2 + 127], 1u);
    atomicAdd(&hc[q3 + 127], 1u);
    pk[0] |= ((unsigned int)(uint8_t)(int8_t)q0) << (8 * j);
    pk[1] |= ((unsigned int)(uint8_t)(int8_t)q1) << (8 * j);
    pk[2] |= ((unsigned int)(uint8_t)(int8_t)q2) << (8 * j);
    pk[3] |= ((unsigned int)(uint8_t)(int8_t)q3) << (8 * j);
  }
  #pragma unroll
  for (int i = 0; i < 4; ++i) tile2[(nq * 4 + i) * TSTR + kq] = pk[i];
  __syncthreads();
  {
    int n = t >> 2, c = t & 3;
    uint4 val;
    val.x = tile2[n * TSTR + c * 4 + 0];
    val.y = tile2[n * TSTR + c * 4 + 1];
    val.z = tile2[n * TSTR + c * 4 + 2];
    val.w = tile2[n * TSTR + c * 4 + 3];
    *(uint4*)(qt + (size_t)(n0 + n) * KD + k0 + c * 16) = val;
  }
  __syncthreads();
  {
    int b = threadIdx.x;
    unsigned int sum = 0;
    #pragma unroll
    for (int c = 0; c < NCOPY; ++c) sum += h[c * HSTR + b];
    if (sum) atomicAdd(&hist[((blockIdx.x + blockIdx.y) & (NPART - 1)) * 256 + b], sum);
  }
}

// ---------------- kth-value: sum partials, prefix scan, pick crossing ----------------
__global__ void finalize_kernel(const unsigned int* __restrict__ hist1,
                                const unsigned int* __restrict__ hist2,
                                float* __restrict__ out_k) {
  __shared__ unsigned int c[256];
  __shared__ int result;
  int t = threadIdx.x;
  const unsigned int* h = (blockIdx.x == 0) ? hist1 : hist2;
  unsigned int sum = 0;
  #pragma unroll
  for (int p = 0; p < NPART; ++p) sum += h[p * 256 + t];
  c[t] = sum;
  if (t == 0) result = 127;
  __syncthreads();
  #pragma unroll
  for (int off = 1; off < 256; off <<= 1) {
    unsigned int add = (t >= off) ? c[t - off] : 0u;
    __syncthreads();
    c[t] += add;
    __syncthreads();
  }
  unsigned int prev = (t == 0) ? 0u : c[t - 1];
  if (c[t] >= (unsigned int)KTH && prev < (unsigned int)KTH) result = t - 127;
  __syncthreads();
  if (t == 0) out_k[blockIdx.x] = (float)result;
}

// ---------------- i8 GEMM: 128x64 wave tiles, 2 blocks/CU ----------------
// 256x128 block tile, 256 thr (4 waves 2Mx2N), wave tile 128x64 -> acc 8x4 v4i.
// Geometry change only vs round 8 (sync structure identical, race-proven):
// 12 ds_read per 32 MFMA per K-tile (was 8 per 16) -> LDS-read/MFMA cycle
// ratio 1.33 (was 1.6). BK=64 double-buffer (48KB), 2 blocks/CU desync for
// read<->MFMA overlap, counted vmcnt(6) 1-tile-ahead, 16x16x64 MFMA with the
// verified 0-conflict 16-row swizzle (chunk ^= (row>>1)&3 both sides).
#define NKT 32  // KD/64
__global__ __launch_bounds__(256, 2) void gemm_i8_kernel(
    const int8_t* __restrict__ qa, const int8_t* __restrict__ qb,
    float* __restrict__ out, const unsigned int* __restrict__ sbits) {
  extern __shared__ __align__(16) int8_t L[];  // A bufs [0,32K), B bufs [32K,48K)

  // XCD map (bijective, 2048 = 8*4*64): xcd owns 4-brow stripe x 64 bcols
  int bid = blockIdx.x;
  int xcd = bid & 7;
  int local = bid >> 3;               // 0..255
  int brow = xcd * 4 + (local & 3);   // 0..31  (256-row panels)
  int bcol = local >> 2;              // 0..63  (128-col panels)

  int t = threadIdx.x;
  int lane = t & 63;
  int w = t >> 6;            // 0..3
  int wr = (w >> 1) * 128;   // 0 | 128
  int wc = (w & 1) * 64;     // 0 | 64

  v4i acc[8][4] = {};

  const int8_t* ga = qa + (size_t)brow * 256 * KD;
  const int8_t* gb = qb + (size_t)bcol * 128 * KD;

  int srow = t >> 2;   // 0..63 (row within a 64-row staging pass)
  int sc = t & 3;

  auto STAGE = [&](int k, int buf) {  // 6 gload_lds: 4 A-passes + 2 B-passes
    int8_t* LA = L + buf * 16384;
    int8_t* LB = L + 32768 + buf * 8192;
    int kcol = k * 64;
    #pragma unroll
    for (int j = 0; j < 4; ++j) {
      int row = j * 64 + srow;
      int gc = sc ^ ((row >> 1) & 3);   // pre-swizzled source, linear LDS dest
      gload_lds16(ga + (size_t)row * KD + kcol + gc * 16, LA + row * 64 + sc * 16);
    }
    #pragma unroll
    for (int j = 0; j < 2; ++j) {
      int row = j * 64 + srow;
      int gc = sc ^ ((row >> 1) & 3);
      gload_lds16(gb + (size_t)row * KD + kcol + gc * 16, LB + row * 64 + sc * 16);
    }
  };

  auto COMPUTE = [&](int k) {
    const int8_t* LA = L + (k & 1) * 16384;
    const int8_t* LB = L + 32768 + (k & 1) * 8192;
    v4i aF[8], bF[4];
    #pragma unroll
    for (int n = 0; n < 4; ++n) {
      int row = wc + n * 16 + (lane & 15);
      int c = (lane >> 4) ^ ((row >> 1) & 3);
      bF[n] = *(const v4i*)(LB + row * 64 + c * 16);
    }
    #pragma unroll
    for (int m = 0; m < 8; ++m) {
      int row = wr + m * 16 + (lane & 15);
      int c = (lane >> 4) ^ ((row >> 1) & 3);
      aF[m] = *(const v4i*)(LA + row * 64 + c * 16);
    }
    __builtin_amdgcn_s_setprio(1);
    #pragma unroll
    for (int m = 0; m < 8; ++m)
      #pragma unroll
      for (int n = 0; n < 4; ++n)
        acc[m][n] = __builtin_amdgcn_mfma_i32_16x16x64_i8(aF[m], bF[n], acc[m][n], 0, 0, 0);
    __builtin_amdgcn_s_setprio(0);
  };

  STAGE(0, 0);
  asm volatile("s_waitcnt vmcnt(0)" ::: "memory");
  __builtin_amdgcn_s_barrier();

  for (int k = 0; k < NKT; ++k) {
    if (k + 1 < NKT) {
      STAGE(k + 1, (k + 1) & 1);
      asm volatile("s_waitcnt vmcnt(6)" ::: "memory");  // tile k landed; k+1's 6 in flight
    } else {
      asm volatile("s_waitcnt vmcnt(0)" ::: "memory");
    }
    __builtin_amdgcn_s_barrier();          // all waves see tile k complete
    __builtin_amdgcn_sched_barrier(0);
    COMPUTE(k);
    __builtin_amdgcn_sched_barrier(0);
    __builtin_amdgcn_s_barrier();          // all reads of tile k done -> buf reusable
  }

  float s1 = __uint_as_float(sbits[0]);
  float s2 = __uint_as_float(sbits[1]);
  float scale = s1 * s2 / (127.0f * 127.0f);
  int orow = brow * 256 + wr + ((lane >> 4) * 4);
  int ocol = bcol * 128 + wc + (lane & 15);
  #pragma unroll
  for (int m = 0; m < 8; ++m)
    #pragma unroll
    for (int n = 0; n < 4; ++n)
      #pragma unroll
      for (int r = 0; r < 4; ++r)
        out[(size_t)(orow + m * 16 + r) * ND + (ocol + n * 16)] = (float)acc[m][n][r] * scale;
}

extern "C" void kernel_launch(void* const* d_in, const int* in_sizes, int n_in,
                              void* d_out, int out_size, void* d_ws, size_t ws_size,
                              hipStream_t stream) {
  const float* x1 = (const float*)d_in[0];
  const float* x2 = (const float*)d_in[1];
  float* out = (float*)d_out;
  uint8_t* ws = (uint8_t*)d_ws;

  unsigned int* sbits = (unsigned int*)ws;
  unsigned int* hist1 = (unsigned int*)(ws + 256);
  unsigned int* hist2 = (unsigned int*)(ws + 256 + 8192);
  int8_t* q1  = (int8_t*)(ws + 32768);
  int8_t* q2t = q1 + (size_t)MD * KD;

  const int n4_1 = MD * KD / 4;
  const int n4_2 = KD * ND / 4;

  hipFuncSetAttribute((const void*)gemm_i8_kernel,
                      hipFuncAttributeMaxDynamicSharedMemorySize, 49152);

  hipMemsetAsync(ws, 0, 32768, stream);
  absmax2_kernel<<<dim3(512, 2), 256, 0, stream>>>(x1, x2, sbits);
  quant_hist_kernel<<<1024, 256, 0, stream>>>(x1, q1, n4_1, sbits + 0, hist1);
  transq_kernel<<<dim3(ND / 64, KD / 64), 256, 0, stream>>>(x2, q2t, sbits + 1, hist2);
  finalize_kernel<<<2, 256, 0, stream>>>(hist1, hist2, out + (size_t)MD * ND);
  gemm_i8_kernel<<<2048, 256, 49152, stream>>>(q1, q2t, out, sbits);
}

// Round 10
// 219.640 us; speedup vs baseline: 1.1384x; 1.0400x over previous
//
#include <hip/hip_runtime.h>
#include <stdint.h>

#define MD 8192
#define ND 8192
#define KD 2048
#define KTH 15099494  // int(8192*2048*0.9)

#define NCOPY 16   // privatized LDS histogram copies
#define HSTR 257   // copy stride in words; 257 % 32 == 1 -> distinct banks per copy
#define NPART 8    // global histogram partials

typedef int v4i __attribute__((ext_vector_type(4)));

__device__ __forceinline__ void gload_lds16(const void* g, void* l) {
  __builtin_amdgcn_global_load_lds(
      (const __attribute__((address_space(1))) uint32_t*)g,
      (__attribute__((address_space(3))) uint32_t*)l, 16, 0, 0);
}

// ---------------- absmax: both tensors, ONE global atomic per block ----------------
__global__ void absmax2_kernel(const float* __restrict__ x1, const float* __restrict__ x2,
                               unsigned int* sbits) {
  __shared__ float wred[4];
  const float4* p = (const float4*)(blockIdx.y ? x2 : x1);
  const int n4 = MD * KD / 4;
  int tid = blockIdx.x * blockDim.x + threadIdx.x;
  int stride = gridDim.x * blockDim.x;
  float m = 0.f;
  for (int i = tid; i < n4; i += stride) {
    float4 v = p[i];
    m = fmaxf(m, fmaxf(fmaxf(fabsf(v.x), fabsf(v.y)), fmaxf(fabsf(v.z), fabsf(v.w))));
  }
  #pragma unroll
  for (int off = 32; off; off >>= 1) m = fmaxf(m, __shfl_down(m, off, 64));
  if ((threadIdx.x & 63) == 0) wred[threadIdx.x >> 6] = m;
  __syncthreads();
  if (threadIdx.x == 0) {
    float bm = fmaxf(fmaxf(wred[0], wred[1]), fmaxf(wred[2], wred[3]));
    atomicMax(&sbits[blockIdx.y], __float_as_uint(bm));
  }
}

// ---------------- quantize x1 (row-major keep) + privatized histogram ----------------
__global__ void quant_hist_kernel(const float* __restrict__ x, int8_t* __restrict__ q,
                                  int n4, const unsigned int* sbits, unsigned int* hist) {
  __shared__ unsigned int h[NCOPY * HSTR];
  for (int i = threadIdx.x; i < NCOPY * HSTR; i += blockDim.x) h[i] = 0;
  __syncthreads();
  unsigned int* hc = h + (threadIdx.x & (NCOPY - 1)) * HSTR;
  float s = __uint_as_float(*sbits);
  int tid = blockIdx.x * blockDim.x + threadIdx.x;
  int stride = gridDim.x * blockDim.x;
  const float4* p = (const float4*)x;
  uint32_t* qo = (uint32_t*)q;
  for (int i = tid; i < n4; i += stride) {
    float4 v = p[i];
    int q0 = (int)rintf(v.x / s * 127.0f);   // keep (x/s)*127 order: matches np bit-exactly
    int q1 = (int)rintf(v.y / s * 127.0f);
    int q2 = (int)rintf(v.z / s * 127.0f);
    int q3 = (int)rintf(v.w / s * 127.0f);
    atomicAdd(&hc[q0 + 127], 1u);
    atomicAdd(&hc[q1 + 127], 1u);
    atomicAdd(&hc[q2 + 127], 1u);
    atomicAdd(&hc[q3 + 127], 1u);
    uint32_t packed = (uint32_t)(uint8_t)(int8_t)q0 |
                      ((uint32_t)(uint8_t)(int8_t)q1 << 8) |
                      ((uint32_t)(uint8_t)(int8_t)q2 << 16) |
                      ((uint32_t)(uint8_t)(int8_t)q3 << 24);
    qo[i] = packed;
  }
  __syncthreads();
  {
    int b = threadIdx.x;
    unsigned int sum = 0;
    #pragma unroll
    for (int c = 0; c < NCOPY; ++c) sum += h[c * HSTR + b];
    if (sum) atomicAdd(&hist[(blockIdx.x & (NPART - 1)) * 256 + b], sum);
  }
}

// ---------------- quantize x2 transposed ([K][N] -> q2t[N][K]) + privatized histogram ----
#define TSTR 17
__global__ void transq_kernel(const float* __restrict__ x, int8_t* __restrict__ qt,
                              const unsigned int* sbits, unsigned int* hist) {
  __shared__ unsigned int tile2[64 * TSTR];
  __shared__ unsigned int h[NCOPY * HSTR];
  for (int i = threadIdx.x; i < NCOPY * HSTR; i += blockDim.x) h[i] = 0;
  __syncthreads();
  unsigned int* hc = h + (threadIdx.x & (NCOPY - 1)) * HSTR;
  float s = __uint_as_float(*sbits);
  int n0 = blockIdx.x * 64, k0 = blockIdx.y * 64;
  int t = threadIdx.x;
  int nq = t & 15, kq = t >> 4;
  unsigned int pk[4] = {0, 0, 0, 0};
  #pragma unroll
  for (int j = 0; j < 4; ++j) {
    float4 v = *(const float4*)(x + (size_t)(k0 + kq * 4 + j) * ND + n0 + nq * 4);
    int q0 = (int)rintf(v.x / s * 127.0f);
    int q1 = (int)rintf(v.y / s * 127.0f);
    int q2 = (int)rintf(v.z / s * 127.0f);
    int q3 = (int)rintf(v.w / s * 127.0f);
    atomicAdd(&hc[q0 + 127], 1u);
    atomicAdd(&hc[q1 + 127], 1u);
    atomicAdd(&hc[q2 + 127], 1u);
    atomicAdd(&hc[q3 + 127], 1u);
    pk[0] |= ((unsigned int)(uint8_t)(int8_t)q0) << (8 * j);
    pk[1] |= ((unsigned int)(uint8_t)(int8_t)q1) << (8 * j);
    pk[2] |= ((unsigned int)(uint8_t)(int8_t)q2) << (8 * j);
    pk[3] |= ((unsigned int)(uint8_t)(int8_t)q3) << (8 * j);
  }
  #pragma unroll
  for (int i = 0; i < 4; ++i) tile2[(nq * 4 + i) * TSTR + kq] = pk[i];
  __syncthreads();
  {
    int n = t >> 2, c = t & 3;
    uint4 val;
    val.x = tile2[n * TSTR + c * 4 + 0];
    val.y = tile2[n * TSTR + c * 4 + 1];
    val.z = tile2[n * TSTR + c * 4 + 2];
    val.w = tile2[n * TSTR + c * 4 + 3];
    *(uint4*)(qt + (size_t)(n0 + n) * KD + k0 + c * 16) = val;
  }
  __syncthreads();
  {
    int b = threadIdx.x;
    unsigned int sum = 0;
    #pragma unroll
    for (int c = 0; c < NCOPY; ++c) sum += h[c * HSTR + b];
    if (sum) atomicAdd(&hist[((blockIdx.x + blockIdx.y) & (NPART - 1)) * 256 + b], sum);
  }
}

// ---------------- kth-value: sum partials, prefix scan, pick crossing ----------------
__global__ void finalize_kernel(const unsigned int* __restrict__ hist1,
                                const unsigned int* __restrict__ hist2,
                                float* __restrict__ out_k) {
  __shared__ unsigned int c[256];
  __shared__ int result;
  int t = threadIdx.x;
  const unsigned int* h = (blockIdx.x == 0) ? hist1 : hist2;
  unsigned int sum = 0;
  #pragma unroll
  for (int p = 0; p < NPART; ++p) sum += h[p * 256 + t];
  c[t] = sum;
  if (t == 0) result = 127;
  __syncthreads();
  #pragma unroll
  for (int off = 1; off < 256; off <<= 1) {
    unsigned int add = (t >= off) ? c[t - off] : 0u;
    __syncthreads();
    c[t] += add;
    __syncthreads();
  }
  unsigned int prev = (t == 0) ? 0u : c[t - 1];
  if (c[t] >= (unsigned int)KTH && prev < (unsigned int)KTH) result = t - 127;
  __syncthreads();
  if (t == 0) out_k[blockIdx.x] = (float)result;
}

// ---------------- i8 GEMM: round-3 structure at 5 blocks/CU ----------------
// 128x128 tile, BK=128, single-buffered 32KB LDS, 4 waves (2x2), plain
// __syncthreads. ONLY change vs the 158us round-3 kernel: launch_bounds
// min-waves/EU 2 -> 5, so 5 independent blocks co-reside per CU
// (5 x 32KB = 160KB LDS exactly; VGPR<=64 -> fine). Cross-block desync
// (m114) supplies the stage<->MFMA overlap the explicit pipelines couldn't.
__global__ __launch_bounds__(256, 5) void gemm_i8_kernel(
    const int8_t* __restrict__ qa, const int8_t* __restrict__ qb,
    float* __restrict__ out, const unsigned int* __restrict__ sbits) {
  __shared__ __align__(16) int8_t Asm[128 * 128];
  __shared__ __align__(16) int8_t Bsm[128 * 128];

  // XCD supergroup (bijective, 4096 = 8*8*64): ~4MB working set per XCD ~= L2
  int bid = blockIdx.x;
  int xcd = bid & 7;
  int local = bid >> 3;               // 0..511
  int brow = xcd * 8 + (local & 7);   // 0..63
  int bcol = local >> 3;              // 0..63

  int t = threadIdx.x;
  int lane = t & 63;
  int w = t >> 6;
  int wr = (w >> 1) * 64, wc = (w & 1) * 64;

  v4i acc[4][4] = {};

  const int8_t* ga = qa + (size_t)brow * 128 * KD;
  const int8_t* gb = qb + (size_t)bcol * 128 * KD;

  int srow = t >> 3;     // 0..31 (row within 32-row staging slab)
  int schunk = t & 7;    // swizzled 16B-chunk slot in LDS row

  for (int kt = 0; kt < KD / 128; ++kt) {
    int kbase = kt * 128;
    #pragma unroll
    for (int i = 0; i < 4; ++i) {
      int row = i * 32 + srow;
      int gchunk = schunk ^ (row & 7);  // pre-swizzled global source
      gload_lds16(ga + (size_t)row * KD + kbase + gchunk * 16, Asm + i * 4096 + t * 16);
    }
    #pragma unroll
    for (int i = 0; i < 4; ++i) {
      int row = i * 32 + srow;
      int gchunk = schunk ^ (row & 7);
      gload_lds16(gb + (size_t)row * KD + kbase + gchunk * 16, Bsm + i * 4096 + t * 16);
    }
    __syncthreads();
    #pragma unroll
    for (int kh = 0; kh < 2; ++kh) {
      v4i aF[4], bF[4];
      #pragma unroll
      for (int m = 0; m < 4; ++m) {
        int row = wr + m * 16 + (lane & 15);
        int chunk = (kh * 4 + (lane >> 4)) ^ (row & 7);
        aF[m] = *(const v4i*)(Asm + row * 128 + chunk * 16);
      }
      #pragma unroll
      for (int n = 0; n < 4; ++n) {
        int row = wc + n * 16 + (lane & 15);
        int chunk = (kh * 4 + (lane >> 4)) ^ (row & 7);
        bF[n] = *(const v4i*)(Bsm + row * 128 + chunk * 16);
      }
      #pragma unroll
      for (int m = 0; m < 4; ++m)
        #pragma unroll
        for (int n = 0; n < 4; ++n)
          acc[m][n] = __builtin_amdgcn_mfma_i32_16x16x64_i8(aF[m], bF[n], acc[m][n], 0, 0, 0);
    }
    __syncthreads();
  }

  float s1 = __uint_as_float(sbits[0]);
  float s2 = __uint_as_float(sbits[1]);
  float scale = s1 * s2 / (127.0f * 127.0f);
  int orow = brow * 128 + wr + ((lane >> 4) * 4);
  int ocol = bcol * 128 + wc + (lane & 15);
  #pragma unroll
  for (int m = 0; m < 4; ++m)
    #pragma unroll
    for (int n = 0; n < 4; ++n)
      #pragma unroll
      for (int r = 0; r < 4; ++r)
        out[(size_t)(orow + m * 16 + r) * ND + (ocol + n * 16)] = (float)acc[m][n][r] * scale;
}

extern "C" void kernel_launch(void* const* d_in, const int* in_sizes, int n_in,
                              void* d_out, int out_size, void* d_ws, size_t ws_size,
                              hipStream_t stream) {
  const float* x1 = (const float*)d_in[0];
  const float* x2 = (const float*)d_in[1];
  float* out = (float*)d_out;
  uint8_t* ws = (uint8_t*)d_ws;

  unsigned int* sbits = (unsigned int*)ws;
  unsigned int* hist1 = (unsigned int*)(ws + 256);
  unsigned int* hist2 = (unsigned int*)(ws + 256 + 8192);
  int8_t* q1  = (int8_t*)(ws + 32768);
  int8_t* q2t = q1 + (size_t)MD * KD;

  const int n4_1 = MD * KD / 4;
  const int n4_2 = KD * ND / 4;

  hipMemsetAsync(ws, 0, 32768, stream);
  absmax2_kernel<<<dim3(512, 2), 256, 0, stream>>>(x1, x2, sbits);
  quant_hist_kernel<<<1024, 256, 0, stream>>>(x1, q1, n4_1, sbits + 0, hist1);
  transq_kernel<<<dim3(ND / 64, KD / 64), 256, 0, stream>>>(x2, q2t, sbits + 1, hist2);
  finalize_kernel<<<2, 256, 0, stream>>>(hist1, hist2, out + (size_t)MD * ND);
  gemm_i8_kernel<<<4096, 256, 0, stream>>>(q1, q2t, out, sbits);
}